// Round 2
// 155.195 us; speedup vs baseline: 1.0276x; 1.0276x over previous
//
#include <hip/hip_runtime.h>

// Problem constants: B=8, N=256, D=300, P=128, V=50001
#define NB 8
#define NN 256
#define DD 300
#define PP 128
#define NC 512                          // concat cols = [Wl|Wr|Ws1|We1]
#define OFF_S (NB * NN * NN)            // 524288  start-head element offset
#define OFF_E (NB * NN * NN + NB * NN)  // 526336  end-head element offset

typedef unsigned short u16;
typedef unsigned int   u32;

__device__ __forceinline__ float bf2f(u16 u) {
    union { u32 i; float f; } v;
    v.i = ((u32)u) << 16;
    return v.f;
}
__device__ __forceinline__ u16 f2bf(float f) {
    union { float f; u32 i; } v;
    v.f = f;
    u32 lsb = (v.i >> 16) & 1u;
    v.i += 0x7fffu + lsb;   // round-to-nearest-even
    return (u16)(v.i >> 16);
}

template<bool BF>
__device__ __forceinline__ float4 ld4(const void* base, int idx) {
    if (BF) {
        ushort4 e = *(const ushort4*)((const u16*)base + idx);
        return make_float4(bf2f(e.x), bf2f(e.y), bf2f(e.z), bf2f(e.w));
    } else {
        return *(const float4*)((const float*)base + idx);
    }
}
template<bool BF>
__device__ __forceinline__ float ld1(const void* base, int idx) {
    return BF ? bf2f(((const u16*)base)[idx]) : ((const float*)base)[idx];
}
template<bool BF>
__device__ __forceinline__ void st1(void* base, int idx, float v) {
    if (BF) ((u16*)base)[idx] = f2bf(v);
    else    ((float*)base)[idx] = v;
}
template<bool BF>
__device__ __forceinline__ void st4(void* base, int idx, float4 v) {
    if (BF) {
        ushort4 o = make_ushort4(f2bf(v.x), f2bf(v.y), f2bf(v.z), f2bf(v.w));
        *(ushort4*)((u16*)base + idx) = o;
    } else {
        *(float4*)((float*)base + idx) = v;
    }
}
// acc += relu(l + r) * w, componentwise over l (r, w scalar)
__device__ __forceinline__ float4 rfma4(float4 l, float r, float w, float4 a) {
    a.x = fmaf(fmaxf(l.x + r, 0.f), w, a.x);
    a.y = fmaf(fmaxf(l.y + r, 0.f), w, a.y);
    a.z = fmaf(fmaxf(l.z + r, 0.f), w, a.z);
    a.w = fmaf(fmaxf(l.w + r, 0.f), w, a.w);
    return a;
}

// ---------------------------------------------------------------------------
// Inline bf16-detect (was detect_kernel). Deterministic over the same 1KB of
// emb -> every block/wave computes the identical flag; reads are L2-hot after
// the first wave. Call with the first wave (tid<64); result valid in all lanes.
// ---------------------------------------------------------------------------
__device__ __forceinline__ int flag_wave(const u32* __restrict__ embU) {
    int lane = threadIdx.x & 63;
    int cnt = 0;
    for (int i = lane; i < 256; i += 64) {
        u32 w = embU[i];
        union { u32 u; float f; } v;
        v.u = (w & 0xFFFFu) << 16;
        float a = fabsf(v.f);
        if (a == 0.f || (a >= 0.00390625f && a <= 256.f)) cnt++;
    }
    #pragma unroll
    for (int off = 32; off; off >>= 1) cnt += __shfl_xor(cnt, off, 64);
    return (cnt >= 128) ? 1 : 0;
}

// ---------------------------------------------------------------------------
// prep: WTf[k][c] = (float)Wcat[c][k]. (Body verbatim from passing R7.)
// ---------------------------------------------------------------------------
template<bool BF>
__device__ __forceinline__ void prep_body(
    const void* __restrict__ Wl, const void* __restrict__ Wr,
    const void* __restrict__ Ws1, const void* __restrict__ We1,
    float* __restrict__ WTf, float (*tile)[301])
{
    const int tid = threadIdx.x;
    const int c0  = blockIdx.x * 32;

    for (int e = tid; e < 32 * 75; e += 256) {       // row-major reads
        int r = e / 75;
        int q = e - r * 75;
        int c = c0 + r;
        const void* src = (c < 128) ? Wl : (c < 256) ? Wr
                        : (c < 384) ? Ws1 : We1;
        float4 f = ld4<BF>(src, (c & 127) * DD + 4 * q);
        tile[r][4 * q + 0] = f.x;
        tile[r][4 * q + 1] = f.y;
        tile[r][4 * q + 2] = f.z;
        tile[r][4 * q + 3] = f.w;
    }
    __syncthreads();
    for (int e = tid; e < 300 * 32; e += 256) {      // k-major writes
        int k = e >> 5;
        int c = e & 31;
        WTf[(size_t)k * NC + c0 + c] = tile[c][k];
    }
}

extern "C" __global__ void __launch_bounds__(256)
prep_kernel(const void* __restrict__ Wl, const void* __restrict__ Wr,
            const void* __restrict__ Ws1, const void* __restrict__ We1,
            float* __restrict__ WTf, const u32* __restrict__ embU)
{
    __shared__ float tile[32][301];
    __shared__ int sflag;
    if (threadIdx.x < 64) {
        int f = flag_wave(embU);
        if (threadIdx.x == 0) sflag = f;
    }
    __syncthreads();
    if (sflag) prep_body<true >(Wl, Wr, Ws1, We1, WTf, tile);
    else       prep_body<false>(Wl, Wr, Ws1, We1, WTf, tile);
}

// ---------------------------------------------------------------------------
// tok: 8 tokens/block (grid 256). Wave = matrix; thread owns cols (2l, 2l+1).
// Per k: one coalesced float2 weight read + two broadcast b128 LDS reads +
// 16 FMAs. WTf L2 traffic halves vs 4-tok (157MB vs 314MB). Since grid 256 =
// 1 wave/SIMD, weight loads are software-pipelined 6 deep (192 FMA-issue
// cycles between load and use ~ L2 latency) instead of relying on TLP.
// ---------------------------------------------------------------------------
template<bool BF>
__device__ __forceinline__ void tok_body(
    const int* __restrict__ sent, const void* __restrict__ emb,
    const float* __restrict__ WTf,
    const void* __restrict__ bl,
    const void* __restrict__ bs1, const void* __restrict__ Ws2,
    const void* __restrict__ bs2,
    const void* __restrict__ be1, const void* __restrict__ We2,
    const void* __restrict__ be2,
    float* __restrict__ leftT, float* __restrict__ rightW,
    void* __restrict__ out, float (*sxT)[8], int* sids)
{
    const int tid = threadIdx.x;
    const int t0  = blockIdx.x * 8;

    if (tid < 8) sids[tid] = sent[t0 + tid];
    __syncthreads();

    // Stage 8 tokens token-minor: sxT[k][t].
    for (int e = tid; e < DD * 8; e += 256) {
        int k = e >> 3, t = e & 7;
        sxT[k][t] = ld1<BF>(emb, sids[t] * DD + k);
    }
    __syncthreads();

    float a0[8], a1[8];                  // acc[token] for cols p0, p1
    #pragma unroll
    for (int t = 0; t < 8; ++t) { a0[t] = 0.f; a1[t] = 0.f; }

    const float* wp = WTf + 2 * tid;
#define LW(kk) (*(const float2*)(wp + (size_t)(kk) * NC))
#define FMAK(kk, Wv) do {                                               \
        float4 xa = *(const float4*)&sxT[(kk)][0];                      \
        float4 xb = *(const float4*)&sxT[(kk)][4];                      \
        float wx_ = (Wv).x, wy_ = (Wv).y;                               \
        a0[0]=fmaf(xa.x,wx_,a0[0]); a1[0]=fmaf(xa.x,wy_,a1[0]);         \
        a0[1]=fmaf(xa.y,wx_,a0[1]); a1[1]=fmaf(xa.y,wy_,a1[1]);         \
        a0[2]=fmaf(xa.z,wx_,a0[2]); a1[2]=fmaf(xa.z,wy_,a1[2]);         \
        a0[3]=fmaf(xa.w,wx_,a0[3]); a1[3]=fmaf(xa.w,wy_,a1[3]);         \
        a0[4]=fmaf(xb.x,wx_,a0[4]); a1[4]=fmaf(xb.x,wy_,a1[4]);         \
        a0[5]=fmaf(xb.y,wx_,a0[5]); a1[5]=fmaf(xb.y,wy_,a1[5]);         \
        a0[6]=fmaf(xb.z,wx_,a0[6]); a1[6]=fmaf(xb.z,wy_,a1[6]);         \
        a0[7]=fmaf(xb.w,wx_,a0[7]); a1[7]=fmaf(xb.w,wy_,a1[7]);         \
    } while (0)

    // Depth-6 manual pipeline; 300 = 50 * 6 exactly.
    float2 q0 = LW(0), q1 = LW(1), q2 = LW(2),
           q3 = LW(3), q4 = LW(4), q5 = LW(5);
    for (int k = 0; k < DD; k += 6) {
        float2 u0 = q0, u1 = q1, u2 = q2, u3 = q3, u4 = q4, u5 = q5;
        if (k + 6 < DD) {
            q0 = LW(k + 6);  q1 = LW(k + 7);  q2 = LW(k + 8);
            q3 = LW(k + 9);  q4 = LW(k + 10); q5 = LW(k + 11);
        }
        FMAK(k + 0, u0); FMAK(k + 1, u1); FMAK(k + 2, u2);
        FMAK(k + 3, u3); FMAK(k + 4, u4); FMAK(k + 5, u5);
    }
#undef LW
#undef FMAK

    const int wv = tid >> 6;     // matrix id (wave-uniform)
    const int l  = tid & 63;
    const int p0 = 2 * l, p1 = p0 + 1;

    if (wv == 0) {               // left = x@Wl.T + bl -> leftT[b][p][j]
        float b0 = ld1<BF>(bl, p0), b1 = ld1<BF>(bl, p1);
        const int bb = t0 >> 8, j0 = t0 & 255;   // 8 | 256 -> no b crossing
        float* o0 = leftT + ((size_t)bb * PP + p0) * NN + j0;
        float* o1 = leftT + ((size_t)bb * PP + p1) * NN + j0;
        #pragma unroll
        for (int t = 0; t < 8; ++t) { o0[t] = a0[t] + b0; o1[t] = a1[t] + b1; }
    } else if (wv == 1) {        // right = x@Wr.T -> rightW[t][p]
        #pragma unroll
        for (int t = 0; t < 8; ++t) {
            rightW[(size_t)(t0 + t) * PP + p0] = a0[t];
            rightW[(size_t)(t0 + t) * PP + p1] = a1[t];
        }
    } else {                     // start (wv==2) / end (wv==3) heads
        const void* h1 = (wv == 2) ? bs1 : be1;
        const void* h2 = (wv == 2) ? Ws2 : We2;
        const void* h3 = (wv == 2) ? bs2 : be2;
        float b0 = ld1<BF>(h1, p0), b1 = ld1<BF>(h1, p1);
        float w0h = ld1<BF>(h2, p0), w1h = ld1<BF>(h2, p1);
        float v[8];
        #pragma unroll
        for (int t = 0; t < 8; ++t)
            v[t] = fmaxf(a0[t] + b0, 0.f) * w0h + fmaxf(a1[t] + b1, 0.f) * w1h;
        #pragma unroll
        for (int off = 32; off; off >>= 1) {
            #pragma unroll
            for (int t = 0; t < 8; ++t) v[t] += __shfl_down(v[t], off, 64);
        }
        if (l == 0) {
            float b2 = ld1<BF>(h3, 0);
            int base = (wv == 2) ? OFF_S : OFF_E;
            #pragma unroll
            for (int t = 0; t < 8; ++t)
                st1<BF>(out, base + t0 + t, v[t] + b2);
        }
    }
}

extern "C" __global__ void __launch_bounds__(256)
tok_kernel(const int* __restrict__ sent, const void* __restrict__ emb,
           const float* __restrict__ WTf,
           const void* __restrict__ bl,
           const void* __restrict__ bs1, const void* __restrict__ Ws2,
           const void* __restrict__ bs2,
           const void* __restrict__ be1, const void* __restrict__ We2,
           const void* __restrict__ be2,
           float* __restrict__ leftT, float* __restrict__ rightW,
           void* __restrict__ out)
{
    __shared__ __align__(16) float sxT[DD][8];
    __shared__ int sids[8];
    __shared__ int sflag;
    if (threadIdx.x < 64) {
        int f = flag_wave((const u32*)emb);
        if (threadIdx.x == 0) sflag = f;
    }
    if (threadIdx.x < 8) sids[threadIdx.x] = sent[blockIdx.x * 8 + threadIdx.x];
    __syncthreads();
    if (sflag) {
        tok_body<true >(sent, emb, WTf, bl, bs1, Ws2, bs2, be1, We2, be2,
                        leftT, rightW, out, sxT, sids);
    } else {
        tok_body<false>(sent, emb, WTf, bl, bs1, Ws2, bs2, be1, We2, be2,
                        leftT, rightW, out, sxT, sids);
    }
}

// ---------------------------------------------------------------------------
// big (unchanged body): bigram[b,i,j] = sum_p relu(left[b,j,p]+right[b,i,p])
// * Wo[p] + bo. Grid 512 = (b in 8) x (64 i-tiles of 4). Block 256 = 4 waves;
// wave w covers p-quarter; cross-wave p-reduction through LDS.
// ---------------------------------------------------------------------------
template<bool BF>
__device__ __forceinline__ void big_body(
    const float* __restrict__ leftT, const float* __restrict__ rightW,
    const void* __restrict__ Wo, const void* __restrict__ bo,
    void* __restrict__ outB,
    float (*sR)[128], float* sWo, float4 (*red4)[64][4])
{
    const int tid = threadIdx.x;
    const int b   = blockIdx.x >> 6;
    const int i0  = (blockIdx.x & 63) << 2;

    if (tid < 128) sWo[tid] = ld1<BF>(Wo, tid);
    for (int c = tid; c < 512; c += 256) {
        int i = c >> 7, pp = c & 127;
        sR[i][pp] = rightW[((size_t)(b * NN + i0 + i)) * PP + pp];
    }
    __syncthreads();

    const int w    = tid >> 6;          // p-quarter
    const int lane = tid & 63;
    const int j4   = lane << 2;
    const float* lp = leftT + (size_t)b * PP * NN + j4;

    float4 A0 = {0.f, 0.f, 0.f, 0.f}, A1 = A0, A2 = A0, A3 = A0;
    const int pbase = w * 32;
    #pragma unroll
    for (int g = 0; g < 8; ++g) {
        const int p = pbase + g * 4;
        float4 wo = *(const float4*)&sWo[p];       // broadcast b128
        float4 r0 = *(const float4*)&sR[0][p];
        float4 r1 = *(const float4*)&sR[1][p];
        float4 r2 = *(const float4*)&sR[2][p];
        float4 r3 = *(const float4*)&sR[3][p];
        const float* lpp = lp + (size_t)p * NN;
        float4 l0 = *(const float4*)(lpp);         // coalesced b128
        float4 l1 = *(const float4*)(lpp + NN);
        float4 l2 = *(const float4*)(lpp + 2 * NN);
        float4 l3 = *(const float4*)(lpp + 3 * NN);
        A0 = rfma4(l0, r0.x, wo.x, A0);
        A1 = rfma4(l0, r1.x, wo.x, A1);
        A2 = rfma4(l0, r2.x, wo.x, A2);
        A3 = rfma4(l0, r3.x, wo.x, A3);
        A0 = rfma4(l1, r0.y, wo.y, A0);
        A1 = rfma4(l1, r1.y, wo.y, A1);
        A2 = rfma4(l1, r2.y, wo.y, A2);
        A3 = rfma4(l1, r3.y, wo.y, A3);
        A0 = rfma4(l2, r0.z, wo.z, A0);
        A1 = rfma4(l2, r1.z, wo.z, A1);
        A2 = rfma4(l2, r2.z, wo.z, A2);
        A3 = rfma4(l2, r3.z, wo.z, A3);
        A0 = rfma4(l3, r0.w, wo.w, A0);
        A1 = rfma4(l3, r1.w, wo.w, A1);
        A2 = rfma4(l3, r2.w, wo.w, A2);
        A3 = rfma4(l3, r3.w, wo.w, A3);
    }

    // Cross-wave p-reduction.
    red4[w][lane][0] = A0;
    red4[w][lane][1] = A1;
    red4[w][lane][2] = A2;
    red4[w][lane][3] = A3;
    __syncthreads();

    if (tid < 64) {
        float bov = ld1<BF>(bo, 0);
        #pragma unroll
        for (int i = 0; i < 4; ++i) {
            float4 s0 = red4[0][tid][i];
            float4 s1 = red4[1][tid][i];
            float4 s2 = red4[2][tid][i];
            float4 s3 = red4[3][tid][i];
            float4 s;
            s.x = s0.x + s1.x + s2.x + s3.x + bov;
            s.y = s0.y + s1.y + s2.y + s3.y + bov;
            s.z = s0.z + s1.z + s2.z + s3.z + bov;
            s.w = s0.w + s1.w + s2.w + s3.w + bov;
            st4<BF>(outB, (int)(((size_t)(b * NN + i0 + i)) * NN) + tid * 4, s);
        }
    }
}

extern "C" __global__ void __launch_bounds__(256)
big_kernel(const float* __restrict__ leftT, const float* __restrict__ rightW,
           const void* __restrict__ Wo, const void* __restrict__ bo,
           void* __restrict__ outB, const u32* __restrict__ embU)
{
    __shared__ float sR[4][128];
    __shared__ float sWo[128];
    __shared__ float4 red4[4][64][4];
    __shared__ int sflag;
    if (threadIdx.x < 64) {
        int f = flag_wave(embU);
        if (threadIdx.x == 0) sflag = f;
    }
    __syncthreads();
    if (sflag) big_body<true >(leftT, rightW, Wo, bo, outB, sR, sWo, red4);
    else       big_body<false>(leftT, rightW, Wo, bo, outB, sR, sWo, red4);
}

extern "C" void kernel_launch(void* const* d_in, const int* in_sizes, int n_in,
                              void* d_out, int out_size, void* d_ws, size_t ws_size,
                              hipStream_t stream) {
    const int*  sent = (const int*)d_in[0];
    const void* emb  = d_in[1];
    const void* Wl   = d_in[2];
    const void* bl   = d_in[3];
    const void* Wr   = d_in[4];
    const void* Wo   = d_in[5];
    const void* bo   = d_in[6];
    const void* Ws1  = d_in[7];
    const void* bs1  = d_in[8];
    const void* Ws2  = d_in[9];
    const void* bs2  = d_in[10];
    const void* We1  = d_in[11];
    const void* be1  = d_in[12];
    const void* We2  = d_in[13];
    const void* be2  = d_in[14];

    // ws layout: [pad 1KB][leftT 1MB][rightW 1MB][WTf 300x512 f32]
    float* leftT  = (float*)((char*)d_ws + 1024);
    float* rightW = leftT + (size_t)NB * PP * NN;
    float* WTf    = rightW + (size_t)NB * NN * PP;

    hipLaunchKernelGGL(prep_kernel, dim3(16), dim3(256), 0, stream,
                       Wl, Wr, Ws1, We1, WTf, (const u32*)emb);
    hipLaunchKernelGGL(tok_kernel, dim3(256), dim3(256), 0, stream,
                       sent, emb, WTf, bl, bs1, Ws2, bs2, be1, We2, be2,
                       leftT, rightW, d_out);
    hipLaunchKernelGGL(big_kernel, dim3(512), dim3(256), 0, stream,
                       leftT, rightW, Wo, bo, d_out, (const u32*)emb);
}

// Round 3
// 147.988 us; speedup vs baseline: 1.0776x; 1.0487x over previous
//
#include <hip/hip_runtime.h>

// Problem constants: B=8, N=256, D=300, P=128, V=50001
#define NB 8
#define NN 256
#define DD 300
#define PP 128
#define OFF_S (NB * NN * NN)            // 524288  start-head element offset
#define OFF_E (NB * NN * NN + NB * NN)  // 526336  end-head element offset

typedef unsigned short u16;
typedef unsigned int   u32;

__device__ __forceinline__ float bf2f(u16 u) {
    union { u32 i; float f; } v;
    v.i = ((u32)u) << 16;
    return v.f;
}
__device__ __forceinline__ u16 f2bf(float f) {
    union { float f; u32 i; } v;
    v.f = f;
    u32 lsb = (v.i >> 16) & 1u;
    v.i += 0x7fffu + lsb;   // round-to-nearest-even
    return (u16)(v.i >> 16);
}

template<bool BF>
__device__ __forceinline__ float ld1(const void* base, int idx) {
    return BF ? bf2f(((const u16*)base)[idx]) : ((const float*)base)[idx];
}
template<bool BF>
__device__ __forceinline__ void st1(void* base, int idx, float v) {
    if (BF) ((u16*)base)[idx] = f2bf(v);
    else    ((float*)base)[idx] = v;
}
template<bool BF>
__device__ __forceinline__ void st4(void* base, int idx, float4 v) {
    if (BF) {
        ushort4 o = make_ushort4(f2bf(v.x), f2bf(v.y), f2bf(v.z), f2bf(v.w));
        *(ushort4*)((u16*)base + idx) = o;
    } else {
        *(float4*)((float*)base + idx) = v;
    }
}
// acc += relu(l + r) * w, componentwise over l (r, w scalar)
__device__ __forceinline__ float4 rfma4(float4 l, float r, float w, float4 a) {
    a.x = fmaf(fmaxf(l.x + r, 0.f), w, a.x);
    a.y = fmaf(fmaxf(l.y + r, 0.f), w, a.y);
    a.z = fmaf(fmaxf(l.z + r, 0.f), w, a.z);
    a.w = fmaf(fmaxf(l.w + r, 0.f), w, a.w);
    return a;
}

// Raw weight-register holder: keeps the prefetched value in its storage type
// (ushort4 for bf16) so the bf16->f32 convert happens at USE time, not load
// time — otherwise the cvt would collapse the software pipeline's
// load-to-use distance to zero.
template<bool BF> struct wraw;
template<> struct wraw<false> {
    typedef float4 T;
    static __device__ __forceinline__ T ld(const void* W, int off) {
        return *(const float4*)((const float*)W + off);
    }
    static __device__ __forceinline__ float4 cvt(T v) { return v; }
};
template<> struct wraw<true> {
    typedef ushort4 T;
    static __device__ __forceinline__ T ld(const void* W, int off) {
        return *(const ushort4*)((const u16*)W + off);
    }
    static __device__ __forceinline__ float4 cvt(T v) {
        return make_float4(bf2f(v.x), bf2f(v.y), bf2f(v.z), bf2f(v.w));
    }
};

// ---------------------------------------------------------------------------
// Inline bf16-detect. Deterministic over the same 1KB of emb -> every
// block/wave computes the identical flag; L2-hot after the first wave.
// Call with the first wave (tid<64); result valid in all its lanes.
// ---------------------------------------------------------------------------
__device__ __forceinline__ int flag_wave(const u32* __restrict__ embU) {
    int lane = threadIdx.x & 63;
    int cnt = 0;
    for (int i = lane; i < 256; i += 64) {
        u32 w = embU[i];
        union { u32 u; float f; } v;
        v.u = (w & 0xFFFFu) << 16;
        float a = fabsf(v.f);
        if (a == 0.f || (a >= 0.00390625f && a <= 256.f)) cnt++;
    }
    #pragma unroll
    for (int off = 32; off; off >>= 1) cnt += __shfl_xor(cnt, off, 64);
    return (cnt >= 128) ? 1 : 0;
}

// ---------------------------------------------------------------------------
// tok: 8 tokens/block (grid 256). Wave wv owns matrix wv in [Wl,Wr,Ws1,We1]
// (raw row-major [128][300] — prep/WTf transpose kernel eliminated); lane l
// owns rows (2l, 2l+1). Per 4-k group: 2 aligned row-segment loads (b128 f32
// / b64 bf16, streamed contiguously per thread, L2-hot) + 8 broadcast b128
// LDS reads of x + 64 FMAs. Weight loads software-pipelined 3 groups deep
// (~570 cyc load-to-use >> L2 latency) since grid 256 = 1 wave/SIMD.
// ---------------------------------------------------------------------------
template<bool BF>
__device__ __forceinline__ void tok_body(
    const void* __restrict__ Wl,  const void* __restrict__ Wr,
    const void* __restrict__ Ws1, const void* __restrict__ We1,
    const void* __restrict__ bl,
    const void* __restrict__ bs1, const void* __restrict__ Ws2,
    const void* __restrict__ bs2,
    const void* __restrict__ be1, const void* __restrict__ We2,
    const void* __restrict__ be2,
    const void* __restrict__ emb,
    float* __restrict__ leftT, float* __restrict__ rightW,
    void* __restrict__ out, float (*sxT)[8], const int* sids)
{
    const int tid = threadIdx.x;
    const int t0  = blockIdx.x * 8;

    // Stage 8 tokens token-minor: sxT[k][t].
    for (int e = tid; e < DD * 8; e += 256) {
        int k = e >> 3, t = e & 7;
        sxT[k][t] = ld1<BF>(emb, sids[t] * DD + k);
    }
    __syncthreads();

    const int wv = tid >> 6;     // matrix id (wave-uniform)
    const int l  = tid & 63;
    const int p0 = 2 * l, p1 = p0 + 1;
    const void* Wm = (wv == 0) ? Wl : (wv == 1) ? Wr : (wv == 2) ? Ws1 : We1;
    const int r0 = p0 * DD, r1 = p1 * DD;

    float a0[8], a1[8];                  // acc[token] for rows p0, p1
    #pragma unroll
    for (int t = 0; t < 8; ++t) { a0[t] = 0.f; a1[t] = 0.f; }

#define FMAK(kk, wx_, wy_) do {                                         \
        float4 xa = *(const float4*)&sxT[(kk)][0];                      \
        float4 xb = *(const float4*)&sxT[(kk)][4];                      \
        a0[0]=fmaf(xa.x,wx_,a0[0]); a1[0]=fmaf(xa.x,wy_,a1[0]);         \
        a0[1]=fmaf(xa.y,wx_,a0[1]); a1[1]=fmaf(xa.y,wy_,a1[1]);         \
        a0[2]=fmaf(xa.z,wx_,a0[2]); a1[2]=fmaf(xa.z,wy_,a1[2]);         \
        a0[3]=fmaf(xa.w,wx_,a0[3]); a1[3]=fmaf(xa.w,wy_,a1[3]);         \
        a0[4]=fmaf(xb.x,wx_,a0[4]); a1[4]=fmaf(xb.x,wy_,a1[4]);         \
        a0[5]=fmaf(xb.y,wx_,a0[5]); a1[5]=fmaf(xb.y,wy_,a1[5]);         \
        a0[6]=fmaf(xb.z,wx_,a0[6]); a1[6]=fmaf(xb.z,wy_,a1[6]);         \
        a0[7]=fmaf(xb.w,wx_,a0[7]); a1[7]=fmaf(xb.w,wy_,a1[7]);         \
    } while (0)

#define GROUP(k0, U0, U1) do {                                          \
        float4 f0_ = wraw<BF>::cvt(U0);                                 \
        float4 f1_ = wraw<BF>::cvt(U1);                                 \
        FMAK((k0) + 0, f0_.x, f1_.x);                                   \
        FMAK((k0) + 1, f0_.y, f1_.y);                                   \
        FMAK((k0) + 2, f0_.z, f1_.z);                                   \
        FMAK((k0) + 3, f0_.w, f1_.w);                                   \
    } while (0)

    typedef typename wraw<BF>::T WT;
    // 75 groups of 4 k; 25 iterations x 3 groups, prefetch 3 groups ahead.
    WT w0a = wraw<BF>::ld(Wm, r0 + 0), w1a = wraw<BF>::ld(Wm, r1 + 0);
    WT w0b = wraw<BF>::ld(Wm, r0 + 4), w1b = wraw<BF>::ld(Wm, r1 + 4);
    WT w0c = wraw<BF>::ld(Wm, r0 + 8), w1c = wraw<BF>::ld(Wm, r1 + 8);
    for (int it = 0; it < 25; ++it) {
        WT u0a = w0a, u1a = w1a, u0b = w0b, u1b = w1b, u0c = w0c, u1c = w1c;
        const int kn = it * 12 + 12;
        if (it < 24) {
            w0a = wraw<BF>::ld(Wm, r0 + kn);     w1a = wraw<BF>::ld(Wm, r1 + kn);
            w0b = wraw<BF>::ld(Wm, r0 + kn + 4); w1b = wraw<BF>::ld(Wm, r1 + kn + 4);
            w0c = wraw<BF>::ld(Wm, r0 + kn + 8); w1c = wraw<BF>::ld(Wm, r1 + kn + 8);
        }
        GROUP(it * 12,     u0a, u1a);
        GROUP(it * 12 + 4, u0b, u1b);
        GROUP(it * 12 + 8, u0c, u1c);
    }
#undef GROUP
#undef FMAK

    if (wv == 0) {               // left = x@Wl.T + bl -> leftT[b][p][j]
        float b0 = ld1<BF>(bl, p0), b1 = ld1<BF>(bl, p1);
        const int bb = t0 >> 8, j0 = t0 & 255;   // 8 | 256 -> no b crossing
        float* o0 = leftT + ((size_t)bb * PP + p0) * NN + j0;
        float* o1 = leftT + ((size_t)bb * PP + p1) * NN + j0;
        *(float4*)(o0)     = make_float4(a0[0]+b0, a0[1]+b0, a0[2]+b0, a0[3]+b0);
        *(float4*)(o0 + 4) = make_float4(a0[4]+b0, a0[5]+b0, a0[6]+b0, a0[7]+b0);
        *(float4*)(o1)     = make_float4(a1[0]+b1, a1[1]+b1, a1[2]+b1, a1[3]+b1);
        *(float4*)(o1 + 4) = make_float4(a1[4]+b1, a1[5]+b1, a1[6]+b1, a1[7]+b1);
    } else if (wv == 1) {        // right = x@Wr.T -> rightW[t][p]
        #pragma unroll
        for (int t = 0; t < 8; ++t) {
            *(float2*)&rightW[(size_t)(t0 + t) * PP + p0] =
                make_float2(a0[t], a1[t]);
        }
    } else {                     // start (wv==2) / end (wv==3) heads
        const void* h1 = (wv == 2) ? bs1 : be1;
        const void* h2 = (wv == 2) ? Ws2 : We2;
        const void* h3 = (wv == 2) ? bs2 : be2;
        float b0 = ld1<BF>(h1, p0), b1 = ld1<BF>(h1, p1);
        float w0h = ld1<BF>(h2, p0), w1h = ld1<BF>(h2, p1);
        float v[8];
        #pragma unroll
        for (int t = 0; t < 8; ++t)
            v[t] = fmaxf(a0[t] + b0, 0.f) * w0h + fmaxf(a1[t] + b1, 0.f) * w1h;
        #pragma unroll
        for (int off = 32; off; off >>= 1) {
            #pragma unroll
            for (int t = 0; t < 8; ++t) v[t] += __shfl_down(v[t], off, 64);
        }
        if (l == 0) {
            float b2 = ld1<BF>(h3, 0);
            int base = (wv == 2) ? OFF_S : OFF_E;
            #pragma unroll
            for (int t = 0; t < 8; ++t)
                st1<BF>(out, base + t0 + t, v[t] + b2);
        }
    }
}

extern "C" __global__ void __launch_bounds__(256)
tok_kernel(const int* __restrict__ sent, const void* __restrict__ emb,
           const void* __restrict__ Wl,  const void* __restrict__ Wr,
           const void* __restrict__ Ws1, const void* __restrict__ We1,
           const void* __restrict__ bl,
           const void* __restrict__ bs1, const void* __restrict__ Ws2,
           const void* __restrict__ bs2,
           const void* __restrict__ be1, const void* __restrict__ We2,
           const void* __restrict__ be2,
           float* __restrict__ leftT, float* __restrict__ rightW,
           void* __restrict__ out)
{
    __shared__ __align__(16) float sxT[DD][8];
    __shared__ int sids[8];
    __shared__ int sflag;
    if (threadIdx.x < 64) {
        int f = flag_wave((const u32*)emb);
        if (threadIdx.x == 0) sflag = f;
    }
    if (threadIdx.x < 8) sids[threadIdx.x] = sent[blockIdx.x * 8 + threadIdx.x];
    __syncthreads();
    if (sflag) {
        tok_body<true >(Wl, Wr, Ws1, We1, bl, bs1, Ws2, bs2, be1, We2, be2,
                        emb, leftT, rightW, out, sxT, sids);
    } else {
        tok_body<false>(Wl, Wr, Ws1, We1, bl, bs1, Ws2, bs2, be1, We2, be2,
                        emb, leftT, rightW, out, sxT, sids);
    }
}

// ---------------------------------------------------------------------------
// big (unchanged body): bigram[b,i,j] = sum_p relu(left[b,j,p]+right[b,i,p])
// * Wo[p] + bo. Grid 512 = (b in 8) x (64 i-tiles of 4). Block 256 = 4 waves;
// wave w covers p-quarter; cross-wave p-reduction through LDS.
// ---------------------------------------------------------------------------
template<bool BF>
__device__ __forceinline__ void big_body(
    const float* __restrict__ leftT, const float* __restrict__ rightW,
    const void* __restrict__ Wo, const void* __restrict__ bo,
    void* __restrict__ outB,
    float (*sR)[128], float* sWo, float4 (*red4)[64][4])
{
    const int tid = threadIdx.x;
    const int b   = blockIdx.x >> 6;
    const int i0  = (blockIdx.x & 63) << 2;

    if (tid < 128) sWo[tid] = ld1<BF>(Wo, tid);
    for (int c = tid; c < 512; c += 256) {
        int i = c >> 7, pp = c & 127;
        sR[i][pp] = rightW[((size_t)(b * NN + i0 + i)) * PP + pp];
    }
    __syncthreads();

    const int w    = tid >> 6;          // p-quarter
    const int lane = tid & 63;
    const int j4   = lane << 2;
    const float* lp = leftT + (size_t)b * PP * NN + j4;

    float4 A0 = {0.f, 0.f, 0.f, 0.f}, A1 = A0, A2 = A0, A3 = A0;
    const int pbase = w * 32;
    #pragma unroll
    for (int g = 0; g < 8; ++g) {
        const int p = pbase + g * 4;
        float4 wo = *(const float4*)&sWo[p];       // broadcast b128
        float4 r0 = *(const float4*)&sR[0][p];
        float4 r1 = *(const float4*)&sR[1][p];
        float4 r2 = *(const float4*)&sR[2][p];
        float4 r3 = *(const float4*)&sR[3][p];
        const float* lpp = lp + (size_t)p * NN;
        float4 l0 = *(const float4*)(lpp);         // coalesced b128
        float4 l1 = *(const float4*)(lpp + NN);
        float4 l2 = *(const float4*)(lpp + 2 * NN);
        float4 l3 = *(const float4*)(lpp + 3 * NN);
        A0 = rfma4(l0, r0.x, wo.x, A0);
        A1 = rfma4(l0, r1.x, wo.x, A1);
        A2 = rfma4(l0, r2.x, wo.x, A2);
        A3 = rfma4(l0, r3.x, wo.x, A3);
        A0 = rfma4(l1, r0.y, wo.y, A0);
        A1 = rfma4(l1, r1.y, wo.y, A1);
        A2 = rfma4(l1, r2.y, wo.y, A2);
        A3 = rfma4(l1, r3.y, wo.y, A3);
        A0 = rfma4(l2, r0.z, wo.z, A0);
        A1 = rfma4(l2, r1.z, wo.z, A1);
        A2 = rfma4(l2, r2.z, wo.z, A2);
        A3 = rfma4(l2, r3.z, wo.z, A3);
        A0 = rfma4(l3, r0.w, wo.w, A0);
        A1 = rfma4(l3, r1.w, wo.w, A1);
        A2 = rfma4(l3, r2.w, wo.w, A2);
        A3 = rfma4(l3, r3.w, wo.w, A3);
    }

    // Cross-wave p-reduction.
    red4[w][lane][0] = A0;
    red4[w][lane][1] = A1;
    red4[w][lane][2] = A2;
    red4[w][lane][3] = A3;
    __syncthreads();

    if (tid < 64) {
        float bov = ld1<BF>(bo, 0);
        #pragma unroll
        for (int i = 0; i < 4; ++i) {
            float4 s0 = red4[0][tid][i];
            float4 s1 = red4[1][tid][i];
            float4 s2 = red4[2][tid][i];
            float4 s3 = red4[3][tid][i];
            float4 s;
            s.x = s0.x + s1.x + s2.x + s3.x + bov;
            s.y = s0.y + s1.y + s2.y + s3.y + bov;
            s.z = s0.z + s1.z + s2.z + s3.z + bov;
            s.w = s0.w + s1.w + s2.w + s3.w + bov;
            st4<BF>(outB, (int)(((size_t)(b * NN + i0 + i)) * NN) + tid * 4, s);
        }
    }
}

extern "C" __global__ void __launch_bounds__(256)
big_kernel(const float* __restrict__ leftT, const float* __restrict__ rightW,
           const void* __restrict__ Wo, const void* __restrict__ bo,
           void* __restrict__ outB, const u32* __restrict__ embU)
{
    __shared__ float sR[4][128];
    __shared__ float sWo[128];
    __shared__ float4 red4[4][64][4];
    __shared__ int sflag;
    if (threadIdx.x < 64) {
        int f = flag_wave(embU);
        if (threadIdx.x == 0) sflag = f;
    }
    __syncthreads();
    if (sflag) big_body<true >(leftT, rightW, Wo, bo, outB, sR, sWo, red4);
    else       big_body<false>(leftT, rightW, Wo, bo, outB, sR, sWo, red4);
}

extern "C" void kernel_launch(void* const* d_in, const int* in_sizes, int n_in,
                              void* d_out, int out_size, void* d_ws, size_t ws_size,
                              hipStream_t stream) {
    const int*  sent = (const int*)d_in[0];
    const void* emb  = d_in[1];
    const void* Wl   = d_in[2];
    const void* bl   = d_in[3];
    const void* Wr   = d_in[4];
    const void* Wo   = d_in[5];
    const void* bo   = d_in[6];
    const void* Ws1  = d_in[7];
    const void* bs1  = d_in[8];
    const void* Ws2  = d_in[9];
    const void* bs2  = d_in[10];
    const void* We1  = d_in[11];
    const void* be1  = d_in[12];
    const void* We2  = d_in[13];
    const void* be2  = d_in[14];

    // ws layout: [pad 1KB][leftT 1MB][rightW 1MB]
    float* leftT  = (float*)((char*)d_ws + 1024);
    float* rightW = leftT + (size_t)NB * PP * NN;

    hipLaunchKernelGGL(tok_kernel, dim3(256), dim3(256), 0, stream,
                       sent, emb, Wl, Wr, Ws1, We1, bl, bs1, Ws2, bs2,
                       be1, We2, be2, leftT, rightW, d_out);
    hipLaunchKernelGGL(big_kernel, dim3(512), dim3(256), 0, stream,
                       leftT, rightW, Wo, bo, d_out, (const u32*)emb);
}